// Round 3
// baseline (285.641 us; speedup 1.0000x reference)
//
#include <hip/hip_runtime.h>
#include <hip/hip_bf16.h>
#include <hip/hip_fp16.h>

#define D 128
#define TWO_D 256

typedef _Float16 half2v __attribute__((ext_vector_type(2)));
typedef _Float16 half8v __attribute__((ext_vector_type(8)));
typedef float floatx4 __attribute__((ext_vector_type(4)));

__device__ inline unsigned short f2h_bits(float f) {
    _Float16 h = (_Float16)f;   // v_cvt_f16_f32 (RTN)
    return __builtin_bit_cast(unsigned short, h);
}

__device__ inline unsigned int pkrtz(float a, float b) {
    return __builtin_bit_cast(unsigned int, __builtin_amdgcn_cvt_pkrtz(a, b));
}

// Repack W1[128][256] fp32 -> Wt[o][k] fp16, o in [0,256), k in [0,128)
// o <  128: Wt[o][k] = W1[o][k]           (A-part weights)
// o >= 128: Wt[o][k] = W1[o-128][128+k]   (B-part weights)
__global__ void build_wt(const float* __restrict__ W1, unsigned short* __restrict__ Wt) {
    int idx = blockIdx.x * 256 + threadIdx.x;   // 32768 total
    int o = idx >> 7, k = idx & 127;
    float v = (o < D) ? W1[o * TWO_D + k] : W1[(o - D) * TWO_D + D + k];
    Wt[idx] = f2h_bits(v);
}

// AB[n][o] = sum_k x[n][k] * Wt[o][k] (+ b1[o] for o<128), stored fp16.
// Block = 256 thr (4 waves), 64 nodes per block (4 sub-tiles of 16).
// Wave w owns cols [64w, 64w+64): B-frags resident in 64 VGPRs for whole block.
// x staged via LDS with coalesced float4 loads (fixes the strided-load pathology).
__global__ __launch_bounds__(256) void gemm_nodes(
        const float* __restrict__ x, const unsigned short* __restrict__ Wt,
        const float* __restrict__ b1,
        unsigned short* __restrict__ AB, int nNodes) {
    const int tid  = threadIdx.x;
    const int wave = tid >> 6, lane = tid & 63;
    const int quad = lane >> 4, l16 = lane & 15;
    const int nb0  = blockIdx.x * 64;

    // B-operand frags: o = 64*wave + 16t + l16 (B layout n=lane&15), k = 32ks + 8q..+7
    half8v Bf[4][4];
    float bias[4];
#pragma unroll
    for (int t = 0; t < 4; ++t) {
        const int o = wave * 64 + t * 16 + l16;
        bias[t] = (o < D) ? b1[o] : 0.f;
#pragma unroll
        for (int ks = 0; ks < 4; ++ks)
            Bf[t][ks] = *(const half8v*)(Wt + o * D + ks * 32 + quad * 8);
    }

    // x tile: 16 nodes x 128 fp16, row stride 136 ushorts (272 B, 16B-multiple)
    __shared__ __align__(16) unsigned short xs[16][136];

    const int srow = tid >> 4;   // 0..15  (staging row)
    const int sc8  = tid & 15;   // 0..15  (8-float column block)

    for (int sub = 0; sub < 4; ++sub) {
        const int node = nb0 + sub * 16 + srow;
        const int nc = node < nNodes ? node : nNodes - 1;
        const float* xp = x + nc * D + sc8 * 8;
        floatx4 v0 = *(const floatx4*)xp;          // coalesced: 16 lanes = 512 B row
        floatx4 v1 = *(const floatx4*)(xp + 4);
        uint4 pk;
        pk.x = pkrtz(v0[0], v0[1]);
        pk.y = pkrtz(v0[2], v0[3]);
        pk.z = pkrtz(v1[0], v1[1]);
        pk.w = pkrtz(v1[2], v1[3]);
        __syncthreads();                            // previous sub's readers done
        *(uint4*)&xs[srow][sc8 * 8] = pk;           // one ds_write_b128
        __syncthreads();

        // A-frags: m = lane&15 (node row), k = quad*8 + j + 32*ks
        half8v Af[4];
#pragma unroll
        for (int ks = 0; ks < 4; ++ks)
            Af[ks] = *(const half8v*)&xs[l16][ks * 32 + quad * 8];

        floatx4 acc[4];
#pragma unroll
        for (int t = 0; t < 4; ++t) acc[t] = (floatx4){0.f, 0.f, 0.f, 0.f};
#pragma unroll
        for (int ks = 0; ks < 4; ++ks)
#pragma unroll
            for (int t = 0; t < 4; ++t)
                acc[t] = __builtin_amdgcn_mfma_f32_16x16x32_f16(Af[ks], Bf[t][ks], acc[t], 0, 0, 0);

        // C/D layout: col = lane&15 -> o; row = quad*4 + r -> node
#pragma unroll
        for (int t = 0; t < 4; ++t) {
            const int o = wave * 64 + t * 16 + l16;
#pragma unroll
            for (int r = 0; r < 4; ++r) {
                const int nrow = nb0 + sub * 16 + quad * 4 + r;
                if (nrow < nNodes)
                    AB[nrow * TWO_D + o] = f2h_bits(acc[t][r] + bias[t]);
            }
        }
    }
}

__device__ inline float chunk2(unsigned int a, unsigned int b, unsigned int w, float z) {
    half2v s = __builtin_bit_cast(half2v, a) + __builtin_bit_cast(half2v, b);  // v_pk_add_f16
    half2v zero = {(_Float16)0, (_Float16)0};
    s = __builtin_elementwise_max(s, zero);                                    // v_pk_max_f16
    return __builtin_amdgcn_fdot2(s, __builtin_bit_cast(half2v, w), z, false); // v_dot2_f32_f16
}

// One lane per edge (grid-stride). A' = AB[u][0:128] (bias folded), B = AB[v][128:256].
// h = relu(A'+B) packed fp16; z accumulated fp32 via v_dot2_f32_f16. No shuffles,
// no divergence, no unpack insts.
__global__ __launch_bounds__(256) void edge_loss(
        const unsigned short* __restrict__ AB,
        const int* __restrict__ pairs,
        const float* __restrict__ labels,
        const float* __restrict__ W2,
        const float* __restrict__ b2,
        float* __restrict__ out, int E, float invE) {
    __shared__ unsigned int w2p[64];   // W2 as 64 packed f16 pairs
    const int tid = threadIdx.x;
    if (tid < 64) {
        float2 w = *(const float2*)(W2 + tid * 2);
        half2v p = { (_Float16)w.x, (_Float16)w.y };
        w2p[tid] = __builtin_bit_cast(unsigned int, p);
    }
    __syncthreads();
    const float bb2 = b2[0];

    float acc = 0.f;
    const int stride = gridDim.x * blockDim.x;
    for (int e = blockIdx.x * 256 + tid; e < E; e += stride) {
        const int u = pairs[e];
        const int v = pairs[E + e];
        const unsigned short* au = AB + (size_t)u * TWO_D;        // A'[u][0..]
        const unsigned short* bv = AB + (size_t)v * TWO_D + D;    // B[v][0..]
        float z = bb2;
#pragma unroll
        for (int c = 0; c < 16; ++c) {
            uint4 a4 = *(const uint4*)(au + c * 8);   // 8 fp16, imm-offset loads
            uint4 b4 = *(const uint4*)(bv + c * 8);
            uint4 w4 = *(const uint4*)&w2p[c * 4];    // wave-uniform broadcast
            z = chunk2(a4.x, b4.x, w4.x, z);
            z = chunk2(a4.y, b4.y, w4.y, z);
            z = chunk2(a4.z, b4.z, w4.z, z);
            z = chunk2(a4.w, b4.w, w4.w, z);
        }
        const float y = labels[e];
        // BCE-with-logits, stable: softplus(z) - y*z
        acc += fmaxf(z, 0.f) - z * y + log1pf(__expf(-fabsf(z)));
    }

    // wave shuffle reduce -> LDS -> one atomic per block
#pragma unroll
    for (int m = 32; m >= 1; m >>= 1) acc += __shfl_xor(acc, m, 64);
    __shared__ float red[4];
    if ((tid & 63) == 0) red[tid >> 6] = acc;
    __syncthreads();
    if (tid == 0)
        atomicAdd(out, (red[0] + red[1] + red[2] + red[3]) * invE);
}

extern "C" void kernel_launch(void* const* d_in, const int* in_sizes, int n_in,
                              void* d_out, int out_size, void* d_ws, size_t ws_size,
                              hipStream_t stream) {
    const float* x      = (const float*)d_in[0];
    const float* W1     = (const float*)d_in[1];
    const float* b1     = (const float*)d_in[2];
    const float* W2     = (const float*)d_in[3];
    const float* b2     = (const float*)d_in[4];
    const float* labels = (const float*)d_in[5];
    const int*   pairs  = (const int*)d_in[6];

    const int nNodes = in_sizes[0] / D;   // 50000
    const int E      = in_sizes[5];       // 600000

    unsigned short* Wt = (unsigned short*)d_ws;                    // 64 KiB (fp16)
    unsigned short* AB = (unsigned short*)((char*)d_ws + 65536);   // nNodes*256*2 B (fp16)

    (void)hipMemsetAsync(d_out, 0, sizeof(float), stream);
    build_wt<<<128, 256, 0, stream>>>(W1, Wt);
    gemm_nodes<<<(nNodes + 63) / 64, 256, 0, stream>>>(x, Wt, b1, AB, nNodes);
    edge_loss<<<2048, 256, 0, stream>>>(AB, pairs, labels, W2, b2,
                                        (float*)d_out, E, 1.0f / (float)E);
}

// Round 4
// 148.743 us; speedup vs baseline: 1.9204x; 1.9204x over previous
//
#include <hip/hip_runtime.h>
#include <hip/hip_fp16.h>

#define D 128
#define TWO_D 256

typedef _Float16 half2v __attribute__((ext_vector_type(2)));
typedef _Float16 half8v __attribute__((ext_vector_type(8)));
typedef float floatx4 __attribute__((ext_vector_type(4)));

__device__ inline unsigned short f2h_bits(float f) {
    _Float16 h = (_Float16)f;   // v_cvt_f16_f32 (RTN)
    return __builtin_bit_cast(unsigned short, h);
}

__device__ inline unsigned int pkrtz(float a, float b) {
    return __builtin_bit_cast(unsigned int, __builtin_amdgcn_cvt_pkrtz(a, b));
}

// Repack W1[128][256] fp32 -> Wt[o][k] fp16, o in [0,256), k in [0,128)
__global__ void build_wt(const float* __restrict__ W1, unsigned short* __restrict__ Wt) {
    int idx = blockIdx.x * 256 + threadIdx.x;   // 32768 total
    int o = idx >> 7, k = idx & 127;
    float v = (o < D) ? W1[o * TWO_D + k] : W1[(o - D) * TWO_D + D + k];
    Wt[idx] = f2h_bits(v);
}

// AB[n][o] = sum_k x[n][k]*Wt[o][k] (+b1[o] for o<128), fp16.
// 64 nodes/block (4 sub-tiles of 16). Pipelined: x for sub+1 prefetched into
// regs during sub's MFMA. Epilogue repacked through LDS -> coalesced dwordx4 stores.
__global__ __launch_bounds__(256) void gemm_nodes(
        const float* __restrict__ x, const unsigned short* __restrict__ Wt,
        const float* __restrict__ b1,
        unsigned short* __restrict__ AB, int nNodes) {
    const int tid  = threadIdx.x;
    const int wave = tid >> 6, lane = tid & 63;
    const int quad = lane >> 4, l16 = lane & 15;
    const int nb0  = blockIdx.x * 64;

    // B-operand frags resident in VGPRs: o = 64*wave + 16t + l16, k = 32ks+8q..+7
    half8v Bf[4][4];
    float bias[4];
#pragma unroll
    for (int t = 0; t < 4; ++t) {
        const int o = wave * 64 + t * 16 + l16;
        bias[t] = (o < D) ? b1[o] : 0.f;
#pragma unroll
        for (int ks = 0; ks < 4; ++ks)
            Bf[t][ks] = *(const half8v*)(Wt + o * D + ks * 32 + quad * 8);
    }

    __shared__ __align__(16) unsigned short xs[16][136];  // x tile (fp16), 4.25 KB
    __shared__ __align__(16) unsigned short ct[16][272];  // C repack tile, 8.5 KB

    const int srow = tid >> 4;   // 0..15
    const int sc8  = tid & 15;   // 0..15

    // prefetch sub 0
    floatx4 v0, v1;
    {
        const int node = nb0 + srow;
        const int nc = node < nNodes ? node : nNodes - 1;
        const float* xp = x + nc * D + sc8 * 8;
        v0 = *(const floatx4*)xp;
        v1 = *(const floatx4*)(xp + 4);
    }

    for (int sub = 0; sub < 4; ++sub) {
        __syncthreads();   // prev sub's xs/ct readers done
        uint4 pk;
        pk.x = pkrtz(v0[0], v0[1]);  pk.y = pkrtz(v0[2], v0[3]);
        pk.z = pkrtz(v1[0], v1[1]);  pk.w = pkrtz(v1[2], v1[3]);
        *(uint4*)&xs[srow][sc8 * 8] = pk;
        __syncthreads();   // xs ready

        if (sub < 3) {     // prefetch next sub while this one computes
            const int node = nb0 + (sub + 1) * 16 + srow;
            const int nc = node < nNodes ? node : nNodes - 1;
            const float* xp = x + nc * D + sc8 * 8;
            v0 = *(const floatx4*)xp;
            v1 = *(const floatx4*)(xp + 4);
        }

        half8v Af[4];
#pragma unroll
        for (int ks = 0; ks < 4; ++ks)
            Af[ks] = *(const half8v*)&xs[l16][ks * 32 + quad * 8];

        floatx4 acc[4];
#pragma unroll
        for (int t = 0; t < 4; ++t) acc[t] = (floatx4){0.f, 0.f, 0.f, 0.f};
#pragma unroll
        for (int ks = 0; ks < 4; ++ks)
#pragma unroll
            for (int t = 0; t < 4; ++t)
                acc[t] = __builtin_amdgcn_mfma_f32_16x16x32_f16(Af[ks], Bf[t][ks], acc[t], 0, 0, 0);

        // C/D: col(o) = lane&15 -> o = w*64+t*16+l16 ; row(node-local) = quad*4+r
#pragma unroll
        for (int t = 0; t < 4; ++t) {
            const int o = wave * 64 + t * 16 + l16;
#pragma unroll
            for (int r = 0; r < 4; ++r)
                ct[quad * 4 + r][o] = f2h_bits(acc[t][r] + bias[t]);
        }
        __syncthreads();   // ct ready

        const int nrow = nb0 + sub * 16 + srow;
        if (nrow < nNodes) {
            uint4 c0 = *(const uint4*)&ct[srow][sc8 * 16];
            uint4 c1 = *(const uint4*)&ct[srow][sc8 * 16 + 8];
            unsigned short* dst = AB + (size_t)nrow * TWO_D + sc8 * 16;
            *(uint4*)dst       = c0;       // 16 lanes = 512 B contiguous
            *(uint4*)(dst + 8) = c1;
        }
    }
}

__device__ inline float chunk2(unsigned int a, unsigned int b, unsigned int w, float z) {
    half2v s = __builtin_bit_cast(half2v, a) + __builtin_bit_cast(half2v, b);  // v_pk_add_f16
    half2v zero = {(_Float16)0, (_Float16)0};
    s = __builtin_elementwise_max(s, zero);                                    // v_pk_max_f16
    return __builtin_amdgcn_fdot2(s, __builtin_bit_cast(half2v, w), z, false); // v_dot2_f32_f16
}

// 8 lanes per edge. Each load instruction covers 128 B contiguous (one TCC
// granule): lane l8 reads elems [l8*8, +8) and [64+l8*8, +8) of each row-half.
// Packed fp16 relu+dot, fp32 accum; width-8 butterfly; inline stable softplus.
__global__ __launch_bounds__(256) void edge_loss(
        const unsigned short* __restrict__ AB,
        const int* __restrict__ pairs,
        const float* __restrict__ labels,
        const float* __restrict__ W2,
        const float* __restrict__ b2,
        float* __restrict__ out, int E, float invE) {
    __shared__ unsigned int w2p[64];   // W2 as 64 packed f16 pairs
    const int tid = threadIdx.x;
    if (tid < 64) {
        float2 w = *(const float2*)(W2 + tid * 2);
        half2v p = { (_Float16)w.x, (_Float16)w.y };
        w2p[tid] = __builtin_bit_cast(unsigned int, p);
    }
    __syncthreads();
    const int l8 = tid & 7;
    // lane's W2 chunks: j in [l8*8,+8) and [64+l8*8,+8)
    const uint4 w2a = *(const uint4*)&w2p[l8 * 4];
    const uint4 w2b = *(const uint4*)&w2p[32 + l8 * 4];
    const float bb2 = b2[0];

    float acc = 0.f;
    const int group  = (blockIdx.x * 256 + tid) >> 3;
    const int stride = (gridDim.x * 256) >> 3;
    for (int e = group; e < E; e += stride) {
        const int u = pairs[e];
        const int v = pairs[E + e];
        const unsigned short* au = AB + (size_t)u * TWO_D;        // A'[u][0:128]
        const unsigned short* bv = AB + (size_t)v * TWO_D + D;    // B[v][0:128]
        uint4 a0 = *(const uint4*)(au + l8 * 8);          // 8 lanes = 128 B contig
        uint4 a1 = *(const uint4*)(au + 64 + l8 * 8);
        uint4 b0 = *(const uint4*)(bv + l8 * 8);
        uint4 b1v = *(const uint4*)(bv + 64 + l8 * 8);
        float z = 0.f;
        z = chunk2(a0.x, b0.x, w2a.x, z);
        z = chunk2(a0.y, b0.y, w2a.y, z);
        z = chunk2(a0.z, b0.z, w2a.z, z);
        z = chunk2(a0.w, b0.w, w2a.w, z);
        z = chunk2(a1.x, b1v.x, w2b.x, z);
        z = chunk2(a1.y, b1v.y, w2b.y, z);
        z = chunk2(a1.z, b1v.z, w2b.z, z);
        z = chunk2(a1.w, b1v.w, w2b.w, z);
        // reduce across the 8-lane group
        z += __shfl_xor(z, 4, 8);
        z += __shfl_xor(z, 2, 8);
        z += __shfl_xor(z, 1, 8);
        z += bb2;
        const float y = labels[e];
        // BCE-with-logits, stable: max(z,0) - y*z + ln(1 + exp(-|z|))
        const float t = __expf(-fabsf(z));
        const float loss = fmaxf(z, 0.f) - z * y + __logf(1.f + t);
        acc += (l8 == 0) ? loss : 0.f;
    }

    // wave butterfly -> LDS -> one atomic per block
#pragma unroll
    for (int m = 32; m >= 1; m >>= 1) acc += __shfl_xor(acc, m, 64);
    __shared__ float red[4];
    if ((tid & 63) == 0) red[tid >> 6] = acc;
    __syncthreads();
    if (tid == 0)
        atomicAdd(out, (red[0] + red[1] + red[2] + red[3]) * invE);
}

extern "C" void kernel_launch(void* const* d_in, const int* in_sizes, int n_in,
                              void* d_out, int out_size, void* d_ws, size_t ws_size,
                              hipStream_t stream) {
    const float* x      = (const float*)d_in[0];
    const float* W1     = (const float*)d_in[1];
    const float* b1     = (const float*)d_in[2];
    const float* W2     = (const float*)d_in[3];
    const float* b2     = (const float*)d_in[4];
    const float* labels = (const float*)d_in[5];
    const int*   pairs  = (const int*)d_in[6];

    const int nNodes = in_sizes[0] / D;   // 50000
    const int E      = in_sizes[5];       // 600000

    unsigned short* Wt = (unsigned short*)d_ws;                    // 64 KiB (fp16)
    unsigned short* AB = (unsigned short*)((char*)d_ws + 65536);   // nNodes*256*2 B

    (void)hipMemsetAsync(d_out, 0, sizeof(float), stream);
    build_wt<<<128, 256, 0, stream>>>(W1, Wt);
    gemm_nodes<<<(nNodes + 63) / 64, 256, 0, stream>>>(x, Wt, b1, AB, nNodes);
    edge_loss<<<2048, 256, 0, stream>>>(AB, pairs, labels, W2, b2,
                                        (float*)d_out, E, 1.0f / (float)E);
}

// Round 5
// 140.589 us; speedup vs baseline: 2.0317x; 1.0580x over previous
//
#include <hip/hip_runtime.h>
#include <hip/hip_fp16.h>

#define D 128
#define TWO_D 256

typedef _Float16 half2v __attribute__((ext_vector_type(2)));
typedef _Float16 half8v __attribute__((ext_vector_type(8)));
typedef float floatx4 __attribute__((ext_vector_type(4)));

__device__ inline unsigned int pkrtz(float a, float b) {
    return __builtin_bit_cast(unsigned int, __builtin_amdgcn_cvt_pkrtz(a, b));
}

// AB[n][o] = fp8_e4m3( sum_k x[n][k]*W1eff[o][k] + b1eff[o] ), o in [0,256).
// W1eff[o][k] = (o<128) ? W1[o][k] : W1[o-128][128+k]  (concat-GEMM factorization).
// 64 nodes/block, 4 sub-tiles of 16; B-frags built from W1 fp32 directly (no
// build_wt pass); x pipelined through regs+LDS; epilogue f32->LDS->fp8 repack
// so global stores are coalesced dwordx4 (256 B per row by 16 lanes).
__global__ __launch_bounds__(256) void gemm_nodes(
        const float* __restrict__ x, const float* __restrict__ W1,
        const float* __restrict__ b1,
        unsigned char* __restrict__ AB, float* __restrict__ out0, int nNodes) {
    const int tid  = threadIdx.x;
    const int wave = tid >> 6, lane = tid & 63;
    const int quad = lane >> 4, l16 = lane & 15;
    const int nb0  = blockIdx.x * 64;

    if (blockIdx.x == 0 && tid == 0) *out0 = 0.f;   // replaces hipMemsetAsync

    // B-operand frags in VGPRs: o = 64*wave + 16t + l16 (B layout n=lane&15),
    // k = 32ks + 8*quad + j. Converted fp32->fp16 at load.
    half8v Bf[4][4];
    float bias[4];
#pragma unroll
    for (int t = 0; t < 4; ++t) {
        const int o = wave * 64 + t * 16 + l16;
        bias[t] = (o < D) ? b1[o] : 0.f;
        const float* wrow = (o < D) ? (W1 + (size_t)o * TWO_D)
                                    : (W1 + (size_t)(o - D) * TWO_D + D);
#pragma unroll
        for (int ks = 0; ks < 4; ++ks) {
            const float* wp = wrow + ks * 32 + quad * 8;
            floatx4 w0 = *(const floatx4*)wp;
            floatx4 w1v = *(const floatx4*)(wp + 4);
            uint4 pk;
            pk.x = pkrtz(w0[0], w0[1]);  pk.y = pkrtz(w0[2], w0[3]);
            pk.z = pkrtz(w1v[0], w1v[1]); pk.w = pkrtz(w1v[2], w1v[3]);
            Bf[t][ks] = __builtin_bit_cast(half8v, pk);
        }
    }

    __shared__ __align__(16) unsigned short xs[16][136];  // x tile fp16, 4.25 KB
    __shared__ __align__(16) float ct[16][260];           // C repack tile f32, 16.6 KB

    const int srow = tid >> 4;   // 0..15
    const int sc8  = tid & 15;   // 0..15

    // prefetch sub 0
    floatx4 v0, v1;
    {
        const int node = nb0 + srow;
        const int nc = node < nNodes ? node : nNodes - 1;
        const float* xp = x + (size_t)nc * D + sc8 * 8;
        v0 = *(const floatx4*)xp;
        v1 = *(const floatx4*)(xp + 4);
    }

    for (int sub = 0; sub < 4; ++sub) {
        __syncthreads();   // prev sub's xs/ct readers done
        uint4 pk;
        pk.x = pkrtz(v0[0], v0[1]);  pk.y = pkrtz(v0[2], v0[3]);
        pk.z = pkrtz(v1[0], v1[1]);  pk.w = pkrtz(v1[2], v1[3]);
        *(uint4*)&xs[srow][sc8 * 8] = pk;
        __syncthreads();   // xs ready

        if (sub < 3) {     // prefetch next sub during MFMA
            const int node = nb0 + (sub + 1) * 16 + srow;
            const int nc = node < nNodes ? node : nNodes - 1;
            const float* xp = x + (size_t)nc * D + sc8 * 8;
            v0 = *(const floatx4*)xp;
            v1 = *(const floatx4*)(xp + 4);
        }

        // A-frags: m = lane&15 (node), k = quad*8 + j + 32*ks
        half8v Af[4];
#pragma unroll
        for (int ks = 0; ks < 4; ++ks)
            Af[ks] = *(const half8v*)&xs[l16][ks * 32 + quad * 8];

        floatx4 acc[4];
#pragma unroll
        for (int t = 0; t < 4; ++t) acc[t] = (floatx4){0.f, 0.f, 0.f, 0.f};
#pragma unroll
        for (int ks = 0; ks < 4; ++ks)
#pragma unroll
            for (int t = 0; t < 4; ++t)
                acc[t] = __builtin_amdgcn_mfma_f32_16x16x32_f16(Af[ks], Bf[t][ks], acc[t], 0, 0, 0);

        // C/D: col(o) = lane&15; row(node-local) = quad*4 + r. Stage f32 in LDS.
#pragma unroll
        for (int t = 0; t < 4; ++t) {
            const int o = wave * 64 + t * 16 + l16;
#pragma unroll
            for (int r = 0; r < 4; ++r)
                ct[quad * 4 + r][o] = acc[t][r] + bias[t];
        }
        __syncthreads();   // ct ready

        const int nrow = nb0 + sub * 16 + srow;
        if (nrow < nNodes) {
            floatx4 f0 = *(const floatx4*)&ct[srow][sc8 * 16];
            floatx4 f1 = *(const floatx4*)&ct[srow][sc8 * 16 + 4];
            floatx4 f2 = *(const floatx4*)&ct[srow][sc8 * 16 + 8];
            floatx4 f3 = *(const floatx4*)&ct[srow][sc8 * 16 + 12];
            uint4 o8;
            int d;
            d = __builtin_amdgcn_cvt_pk_fp8_f32(f0[0], f0[1], 0, false);
            d = __builtin_amdgcn_cvt_pk_fp8_f32(f0[2], f0[3], d, true);
            o8.x = (unsigned int)d;
            d = __builtin_amdgcn_cvt_pk_fp8_f32(f1[0], f1[1], 0, false);
            d = __builtin_amdgcn_cvt_pk_fp8_f32(f1[2], f1[3], d, true);
            o8.y = (unsigned int)d;
            d = __builtin_amdgcn_cvt_pk_fp8_f32(f2[0], f2[1], 0, false);
            d = __builtin_amdgcn_cvt_pk_fp8_f32(f2[2], f2[3], d, true);
            o8.z = (unsigned int)d;
            d = __builtin_amdgcn_cvt_pk_fp8_f32(f3[0], f3[1], 0, false);
            d = __builtin_amdgcn_cvt_pk_fp8_f32(f3[2], f3[3], d, true);
            o8.w = (unsigned int)d;
            *(uint4*)(AB + (size_t)nrow * TWO_D + sc8 * 16) = o8;  // 16 lanes = 256 B
        }
    }
}

// relu(a+b) dot w2 for 4 fp8 elements packed in dwords wa/wb; w2 as 2 f16-pairs.
__device__ inline float dot4_fp8(unsigned int wa, unsigned int wb,
                                 unsigned int w2lo, unsigned int w2hi, float z) {
#if __has_builtin(__builtin_amdgcn_cvt_pk_f16_fp8)
    half2v a01 = __builtin_bit_cast(half2v, __builtin_amdgcn_cvt_pk_f16_fp8((short)(wa & 0xffffu)));
    half2v a23 = __builtin_bit_cast(half2v, __builtin_amdgcn_cvt_pk_f16_fp8((short)(wa >> 16)));
    half2v b01 = __builtin_bit_cast(half2v, __builtin_amdgcn_cvt_pk_f16_fp8((short)(wb & 0xffffu)));
    half2v b23 = __builtin_bit_cast(half2v, __builtin_amdgcn_cvt_pk_f16_fp8((short)(wb >> 16)));
    half2v zero = {(_Float16)0, (_Float16)0};
    half2v s01 = __builtin_elementwise_max(a01 + b01, zero);
    half2v s23 = __builtin_elementwise_max(a23 + b23, zero);
    z = __builtin_amdgcn_fdot2(s01, __builtin_bit_cast(half2v, w2lo), z, false);
    z = __builtin_amdgcn_fdot2(s23, __builtin_bit_cast(half2v, w2hi), z, false);
#else
    auto a01 = __builtin_amdgcn_cvt_pk_f32_fp8(wa, false);
    auto a23 = __builtin_amdgcn_cvt_pk_f32_fp8(wa, true);
    auto b01 = __builtin_amdgcn_cvt_pk_f32_fp8(wb, false);
    auto b23 = __builtin_amdgcn_cvt_pk_f32_fp8(wb, true);
    half2v wlo = __builtin_bit_cast(half2v, w2lo);
    half2v whi = __builtin_bit_cast(half2v, w2hi);
    float s0 = fmaxf(a01[0] + b01[0], 0.f), s1 = fmaxf(a01[1] + b01[1], 0.f);
    float s2 = fmaxf(a23[0] + b23[0], 0.f), s3 = fmaxf(a23[1] + b23[1], 0.f);
    z = fmaf(s0, (float)wlo[0], z); z = fmaf(s1, (float)wlo[1], z);
    z = fmaf(s2, (float)whi[0], z); z = fmaf(s3, (float)whi[1], z);
#endif
    return z;
}

// 8 lanes per edge; each gather load = 128 B contiguous (one TCC granule):
// lane l8 holds elements j in [16*l8, 16*l8+16) of each 128-elem half.
// fp8 storage halves gather traffic vs fp16 (256 B/edge).
__global__ __launch_bounds__(256) void edge_loss(
        const unsigned char* __restrict__ AB,
        const int* __restrict__ pairs,
        const float* __restrict__ labels,
        const float* __restrict__ W2,
        const float* __restrict__ b2,
        float* __restrict__ out, int E, float invE) {
    __shared__ unsigned int w2p[64];   // W2 as 64 packed f16 pairs
    const int tid = threadIdx.x;
    if (tid < 64) {
        float2 w = *(const float2*)(W2 + tid * 2);
        half2v p = { (_Float16)w.x, (_Float16)w.y };
        w2p[tid] = __builtin_bit_cast(unsigned int, p);
    }
    __syncthreads();
    const int l8 = tid & 7;
    const uint4 w2a = *(const uint4*)&w2p[l8 * 8];       // pairs for j in [16l8, +8)
    const uint4 w2b = *(const uint4*)&w2p[l8 * 8 + 4];   // pairs for j in [16l8+8, +8)
    const float bb2 = b2[0];

    float acc = 0.f;
    const int group  = (blockIdx.x * 256 + tid) >> 3;
    const int stride = (gridDim.x * 256) >> 3;
    for (int e = group; e < E; e += stride) {
        const int u = pairs[e];
        const int v = pairs[E + e];
        const unsigned char* au = AB + (size_t)u * TWO_D;        // A'[u] fp8[128]
        const unsigned char* bv = AB + (size_t)v * TWO_D + D;    // B[v]  fp8[128]
        uint4 a4 = *(const uint4*)(au + l8 * 16);    // 8 lanes = 128 B contig
        uint4 b4 = *(const uint4*)(bv + l8 * 16);
        float z = 0.f;
        z = dot4_fp8(a4.x, b4.x, w2a.x, w2a.y, z);
        z = dot4_fp8(a4.y, b4.y, w2a.z, w2a.w, z);
        z = dot4_fp8(a4.z, b4.z, w2b.x, w2b.y, z);
        z = dot4_fp8(a4.w, b4.w, w2b.z, w2b.w, z);
        // reduce across the 8-lane group
        z += __shfl_xor(z, 4, 8);
        z += __shfl_xor(z, 2, 8);
        z += __shfl_xor(z, 1, 8);
        z += bb2;
        const float y = labels[e];
        // BCE-with-logits, stable: max(z,0) - y*z + ln(1 + exp(-|z|))
        const float t = __expf(-fabsf(z));
        const float loss = fmaxf(z, 0.f) - z * y + __logf(1.f + t);
        acc += (l8 == 0) ? loss : 0.f;
    }

    // wave butterfly -> LDS -> one atomic per block
#pragma unroll
    for (int m = 32; m >= 1; m >>= 1) acc += __shfl_xor(acc, m, 64);
    __shared__ float red[4];
    if ((tid & 63) == 0) red[tid >> 6] = acc;
    __syncthreads();
    if (tid == 0)
        atomicAdd(out, (red[0] + red[1] + red[2] + red[3]) * invE);
}

extern "C" void kernel_launch(void* const* d_in, const int* in_sizes, int n_in,
                              void* d_out, int out_size, void* d_ws, size_t ws_size,
                              hipStream_t stream) {
    const float* x      = (const float*)d_in[0];
    const float* W1     = (const float*)d_in[1];
    const float* b1     = (const float*)d_in[2];
    const float* W2     = (const float*)d_in[3];
    const float* b2     = (const float*)d_in[4];
    const float* labels = (const float*)d_in[5];
    const int*   pairs  = (const int*)d_in[6];

    const int nNodes = in_sizes[0] / D;   // 50000
    const int E      = in_sizes[5];       // 600000

    unsigned char* AB = (unsigned char*)d_ws;   // nNodes*256 fp8 bytes (12.8 MB)

    gemm_nodes<<<(nNodes + 63) / 64, 256, 0, stream>>>(x, W1, b1, AB,
                                                        (float*)d_out, nNodes);
    edge_loss<<<2048, 256, 0, stream>>>(AB, pairs, labels, W2, b2,
                                        (float*)d_out, E, 1.0f / (float)E);
}

// Round 6
// 137.581 us; speedup vs baseline: 2.0762x; 1.0219x over previous
//
#include <hip/hip_runtime.h>
#include <hip/hip_fp16.h>

#define D 128
#define TWO_D 256

typedef _Float16 half2v __attribute__((ext_vector_type(2)));
typedef _Float16 half8v __attribute__((ext_vector_type(8)));
typedef float floatx4 __attribute__((ext_vector_type(4)));

__device__ inline unsigned int pkrtz(float a, float b) {
    return __builtin_bit_cast(unsigned int, __builtin_amdgcn_cvt_pkrtz(a, b));
}

// AB[n][o] = fp8_e4m3( sum_k x[n][k]*W1eff[o][k] + b1eff[o] ), o in [0,256).
// W1eff[o][k] = (o<128) ? W1[o][k] : W1[o-128][128+k]  (concat-GEMM factorization).
// 64 nodes/block, 4 sub-tiles of 16; B-frags built from W1 fp32 directly;
// x pipelined through regs+LDS; epilogue f32->LDS->fp8 repack for coalesced stores.
__global__ __launch_bounds__(256) void gemm_nodes(
        const float* __restrict__ x, const float* __restrict__ W1,
        const float* __restrict__ b1,
        unsigned char* __restrict__ AB, float* __restrict__ out0, int nNodes) {
    const int tid  = threadIdx.x;
    const int wave = tid >> 6, lane = tid & 63;
    const int quad = lane >> 4, l16 = lane & 15;
    const int nb0  = blockIdx.x * 64;

    if (blockIdx.x == 0 && tid == 0) *out0 = 0.f;   // replaces hipMemsetAsync

    // B-operand frags in VGPRs: o = 64*wave + 16t + l16 (B layout n=lane&15),
    // k = 32ks + 8*quad + j. Converted fp32->fp16 at load.
    half8v Bf[4][4];
    float bias[4];
#pragma unroll
    for (int t = 0; t < 4; ++t) {
        const int o = wave * 64 + t * 16 + l16;
        bias[t] = (o < D) ? b1[o] : 0.f;
        const float* wrow = (o < D) ? (W1 + (size_t)o * TWO_D)
                                    : (W1 + (size_t)(o - D) * TWO_D + D);
#pragma unroll
        for (int ks = 0; ks < 4; ++ks) {
            const float* wp = wrow + ks * 32 + quad * 8;
            floatx4 w0 = *(const floatx4*)wp;
            floatx4 w1v = *(const floatx4*)(wp + 4);
            uint4 pk;
            pk.x = pkrtz(w0[0], w0[1]);  pk.y = pkrtz(w0[2], w0[3]);
            pk.z = pkrtz(w1v[0], w1v[1]); pk.w = pkrtz(w1v[2], w1v[3]);
            Bf[t][ks] = __builtin_bit_cast(half8v, pk);
        }
    }

    __shared__ __align__(16) unsigned short xs[16][136];  // x tile fp16, 4.25 KB
    __shared__ __align__(16) float ct[16][260];           // C repack tile f32, 16.6 KB

    const int srow = tid >> 4;   // 0..15
    const int sc8  = tid & 15;   // 0..15

    // prefetch sub 0
    floatx4 v0, v1;
    {
        const int node = nb0 + srow;
        const int nc = node < nNodes ? node : nNodes - 1;
        const float* xp = x + (size_t)nc * D + sc8 * 8;
        v0 = *(const floatx4*)xp;
        v1 = *(const floatx4*)(xp + 4);
    }

    for (int sub = 0; sub < 4; ++sub) {
        __syncthreads();   // prev sub's xs/ct readers done
        uint4 pk;
        pk.x = pkrtz(v0[0], v0[1]);  pk.y = pkrtz(v0[2], v0[3]);
        pk.z = pkrtz(v1[0], v1[1]);  pk.w = pkrtz(v1[2], v1[3]);
        *(uint4*)&xs[srow][sc8 * 8] = pk;
        __syncthreads();   // xs ready

        if (sub < 3) {     // prefetch next sub during MFMA
            const int node = nb0 + (sub + 1) * 16 + srow;
            const int nc = node < nNodes ? node : nNodes - 1;
            const float* xp = x + (size_t)nc * D + sc8 * 8;
            v0 = *(const floatx4*)xp;
            v1 = *(const floatx4*)(xp + 4);
        }

        // A-frags: m = lane&15 (node), k = quad*8 + j + 32*ks
        half8v Af[4];
#pragma unroll
        for (int ks = 0; ks < 4; ++ks)
            Af[ks] = *(const half8v*)&xs[l16][ks * 32 + quad * 8];

        floatx4 acc[4];
#pragma unroll
        for (int t = 0; t < 4; ++t) acc[t] = (floatx4){0.f, 0.f, 0.f, 0.f};
#pragma unroll
        for (int ks = 0; ks < 4; ++ks)
#pragma unroll
            for (int t = 0; t < 4; ++t)
                acc[t] = __builtin_amdgcn_mfma_f32_16x16x32_f16(Af[ks], Bf[t][ks], acc[t], 0, 0, 0);

        // C/D: col(o) = lane&15; row(node-local) = quad*4 + r. Stage f32 in LDS.
#pragma unroll
        for (int t = 0; t < 4; ++t) {
            const int o = wave * 64 + t * 16 + l16;
#pragma unroll
            for (int r = 0; r < 4; ++r)
                ct[quad * 4 + r][o] = acc[t][r] + bias[t];
        }
        __syncthreads();   // ct ready

        const int nrow = nb0 + sub * 16 + srow;
        if (nrow < nNodes) {
            floatx4 f0 = *(const floatx4*)&ct[srow][sc8 * 16];
            floatx4 f1 = *(const floatx4*)&ct[srow][sc8 * 16 + 4];
            floatx4 f2 = *(const floatx4*)&ct[srow][sc8 * 16 + 8];
            floatx4 f3 = *(const floatx4*)&ct[srow][sc8 * 16 + 12];
            uint4 o8;
            int d;
            d = __builtin_amdgcn_cvt_pk_fp8_f32(f0[0], f0[1], 0, false);
            d = __builtin_amdgcn_cvt_pk_fp8_f32(f0[2], f0[3], d, true);
            o8.x = (unsigned int)d;
            d = __builtin_amdgcn_cvt_pk_fp8_f32(f1[0], f1[1], 0, false);
            d = __builtin_amdgcn_cvt_pk_fp8_f32(f1[2], f1[3], d, true);
            o8.y = (unsigned int)d;
            d = __builtin_amdgcn_cvt_pk_fp8_f32(f2[0], f2[1], 0, false);
            d = __builtin_amdgcn_cvt_pk_fp8_f32(f2[2], f2[3], d, true);
            o8.z = (unsigned int)d;
            d = __builtin_amdgcn_cvt_pk_fp8_f32(f3[0], f3[1], 0, false);
            d = __builtin_amdgcn_cvt_pk_fp8_f32(f3[2], f3[3], d, true);
            o8.w = (unsigned int)d;
            *(uint4*)(AB + (size_t)nrow * TWO_D + sc8 * 16) = o8;  // 16 lanes = 256 B
        }
    }
}

// relu(a+b) dot w2 for 4 fp8 elements packed in dwords wa/wb; w2 as 2 f16-pairs.
__device__ inline float dot4_fp8(unsigned int wa, unsigned int wb,
                                 unsigned int w2lo, unsigned int w2hi, float z) {
#if __has_builtin(__builtin_amdgcn_cvt_pk_f16_fp8)
    half2v a01 = __builtin_bit_cast(half2v, __builtin_amdgcn_cvt_pk_f16_fp8((short)(wa & 0xffffu)));
    half2v a23 = __builtin_bit_cast(half2v, __builtin_amdgcn_cvt_pk_f16_fp8((short)(wa >> 16)));
    half2v b01 = __builtin_bit_cast(half2v, __builtin_amdgcn_cvt_pk_f16_fp8((short)(wb & 0xffffu)));
    half2v b23 = __builtin_bit_cast(half2v, __builtin_amdgcn_cvt_pk_f16_fp8((short)(wb >> 16)));
    half2v zero = {(_Float16)0, (_Float16)0};
    half2v s01 = __builtin_elementwise_max(a01 + b01, zero);
    half2v s23 = __builtin_elementwise_max(a23 + b23, zero);
    z = __builtin_amdgcn_fdot2(s01, __builtin_bit_cast(half2v, w2lo), z, false);
    z = __builtin_amdgcn_fdot2(s23, __builtin_bit_cast(half2v, w2hi), z, false);
#else
    auto a01 = __builtin_amdgcn_cvt_pk_f32_fp8(wa, false);
    auto a23 = __builtin_amdgcn_cvt_pk_f32_fp8(wa, true);
    auto b01 = __builtin_amdgcn_cvt_pk_f32_fp8(wb, false);
    auto b23 = __builtin_amdgcn_cvt_pk_f32_fp8(wb, true);
    half2v wlo = __builtin_bit_cast(half2v, w2lo);
    half2v whi = __builtin_bit_cast(half2v, w2hi);
    float s0 = fmaxf(a01[0] + b01[0], 0.f), s1 = fmaxf(a01[1] + b01[1], 0.f);
    float s2 = fmaxf(a23[0] + b23[0], 0.f), s3 = fmaxf(a23[1] + b23[1], 0.f);
    z = fmaf(s0, (float)wlo[0], z); z = fmaf(s1, (float)wlo[1], z);
    z = fmaf(s2, (float)whi[0], z); z = fmaf(s3, (float)whi[1], z);
#endif
    return z;
}

// One edge's relu-dot for this lane (16 fp8 elems of each half-row).
__device__ inline float edge_dot(const unsigned char* __restrict__ AB,
                                 int u, int v, int l8,
                                 const uint4& w2a, const uint4& w2b) {
    const unsigned char* au = AB + (size_t)u * TWO_D;        // A'[u] fp8[128]
    const unsigned char* bv = AB + (size_t)v * TWO_D + D;    // B[v]  fp8[128]
    uint4 a4 = *(const uint4*)(au + l8 * 16);    // 8 lanes = 128 B contig
    uint4 b4 = *(const uint4*)(bv + l8 * 16);
    float z = 0.f;
    z = dot4_fp8(a4.x, b4.x, w2a.x, w2a.y, z);
    z = dot4_fp8(a4.y, b4.y, w2a.z, w2a.w, z);
    z = dot4_fp8(a4.z, b4.z, w2b.x, w2b.y, z);
    z = dot4_fp8(a4.w, b4.w, w2b.z, w2b.w, z);
    return z;
}

__device__ inline float red8(float z) {
    z += __shfl_xor(z, 4, 8);
    z += __shfl_xor(z, 2, 8);
    z += __shfl_xor(z, 1, 8);
    return z;
}

__device__ inline float bce(float z, float y) {
    const float t = __expf(-fabsf(z));
    return fmaxf(z, 0.f) - z * y + __logf(1.f + t);
}

// 8 lanes per edge; grid-stride UNROLLED x2: two independent edge streams per
// iteration -> 4 independent 128B gathers + 2 index loads in flight per lane.
// This is the MLP fix for the latency-bound gather (R5 lesson: bytes halved,
// time barely moved -> latency-bound, not byte-bound).
__global__ __launch_bounds__(256) void edge_loss(
        const unsigned char* __restrict__ AB,
        const int* __restrict__ pairs,
        const float* __restrict__ labels,
        const float* __restrict__ W2,
        const float* __restrict__ b2,
        float* __restrict__ out, int E, float invE) {
    __shared__ unsigned int w2p[64];   // W2 as 64 packed f16 pairs
    const int tid = threadIdx.x;
    if (tid < 64) {
        float2 w = *(const float2*)(W2 + tid * 2);
        half2v p = { (_Float16)w.x, (_Float16)w.y };
        w2p[tid] = __builtin_bit_cast(unsigned int, p);
    }
    __syncthreads();
    const int l8 = tid & 7;
    const uint4 w2a = *(const uint4*)&w2p[l8 * 8];       // pairs for j in [16l8, +8)
    const uint4 w2b = *(const uint4*)&w2p[l8 * 8 + 4];   // pairs for j in [16l8+8, +8)
    const float bb2 = b2[0];

    float acc = 0.f;
    const int group  = (blockIdx.x * 256 + tid) >> 3;
    const int stride = (gridDim.x * 256) >> 3;

    int e0 = group;
    for (; e0 + stride < E; e0 += 2 * stride) {
        const int e1 = e0 + stride;
        const int u0 = pairs[e0], v0 = pairs[E + e0];
        const int u1 = pairs[e1], v1 = pairs[E + e1];
        float z0 = edge_dot(AB, u0, v0, l8, w2a, w2b);
        float z1 = edge_dot(AB, u1, v1, l8, w2a, w2b);
        z0 = red8(z0) + bb2;
        z1 = red8(z1) + bb2;
        if (l8 == 0) {
            acc += bce(z0, labels[e0]);
            acc += bce(z1, labels[e1]);
        }
    }
    if (e0 < E) {   // at most one tail edge per group
        const int u0 = pairs[e0], v0 = pairs[E + e0];
        float z0 = edge_dot(AB, u0, v0, l8, w2a, w2b);
        z0 = red8(z0) + bb2;
        if (l8 == 0) acc += bce(z0, labels[e0]);
    }

    // wave butterfly -> LDS -> one atomic per block
#pragma unroll
    for (int m = 32; m >= 1; m >>= 1) acc += __shfl_xor(acc, m, 64);
    __shared__ float red[4];
    if ((tid & 63) == 0) red[tid >> 6] = acc;
    __syncthreads();
    if (tid == 0)
        atomicAdd(out, (red[0] + red[1] + red[2] + red[3]) * invE);
}

extern "C" void kernel_launch(void* const* d_in, const int* in_sizes, int n_in,
                              void* d_out, int out_size, void* d_ws, size_t ws_size,
                              hipStream_t stream) {
    const float* x      = (const float*)d_in[0];
    const float* W1     = (const float*)d_in[1];
    const float* b1     = (const float*)d_in[2];
    const float* W2     = (const float*)d_in[3];
    const float* b2     = (const float*)d_in[4];
    const float* labels = (const float*)d_in[5];
    const int*   pairs  = (const int*)d_in[6];

    const int nNodes = in_sizes[0] / D;   // 50000
    const int E      = in_sizes[5];       // 600000

    unsigned char* AB = (unsigned char*)d_ws;   // nNodes*256 fp8 bytes (12.8 MB)

    gemm_nodes<<<(nNodes + 63) / 64, 256, 0, stream>>>(x, W1, b1, AB,
                                                        (float*)d_out, nNodes);
    edge_loss<<<2048, 256, 0, stream>>>(AB, pairs, labels, W2, b2,
                                        (float*)d_out, E, 1.0f / (float)E);
}